// Round 11
// baseline (154.172 us; speedup 1.0000x reference)
//
#include <hip/hip_runtime.h>
#include <hip/hip_bf16.h>

typedef _Float16 half8v __attribute__((ext_vector_type(8)));
typedef _Float16 half4v __attribute__((ext_vector_type(4)));
typedef _Float16 half2v __attribute__((ext_vector_type(2)));
typedef __fp16   fp16x2 __attribute__((ext_vector_type(2)));
typedef __attribute__((ext_vector_type(4))) float floatx4;

#define LOG2E_OVER_8 0.18033688011112042f

// ===== Frag-order layouts (verified r9/r10) =================================
// Kh chunk(t16,c): ((t16*2+c)*64 + quad*16 + m)*8 halves  (A-frag 16x16x32)
// Qh: same with m=q%16. Vh chunk(t64,dt,ktp): (((t64*8)+dt*2+ktp)*64+quad*16+m)*8
// Wt: ((ctg*16+kc)*64 + quad*16 + m)*8

// ---------------- Kernel 0: W -> frag-order Wt fp16 -------------------------
__global__ __launch_bounds__(256) void wtrans_k(const float* __restrict__ Wq,
                                                const float* __restrict__ Wk,
                                                const float* __restrict__ Wv,
                                                _Float16* __restrict__ Wt) {
    int idx = blockIdx.x * 256 + threadIdx.x;   // 98304 = 3*512*64
    int p = idx >> 15, rem = idx & 32767;
    int k = rem >> 6;      // input row
    int n = rem & 63;      // input col (lane-fast -> coalesced read)
    const float* W = (p == 0) ? Wq : ((p == 1) ? Wk : Wv);
    int ctg = p * 4 + (n >> 4), m = n & 15;
    int kc = k >> 5, quad = (k >> 3) & 3, j = k & 7;
    Wt[(((ctg << 4) + kc) * 64 + (quad << 4) + m) * 8 + j] = (_Float16)W[k * 64 + n];
}

// ---------------- Kernel 1: QKV projection (verified r9/r10) ----------------
#define XS_STRIDE 536
__global__ __launch_bounds__(256) void proj_k(const float* __restrict__ x,
                                              const _Float16* __restrict__ Wt,
                                              const float* __restrict__ bq,
                                              const float* __restrict__ bk,
                                              const float* __restrict__ bv,
                                              _Float16* __restrict__ Qh,
                                              _Float16* __restrict__ Kh,
                                              _Float16* __restrict__ Vh) {
    __shared__ _Float16 xs[16 * XS_STRIDE];

    int tid = threadIdx.x, l = tid & 63, wv = tid >> 6;
    int m = l & 15, quad = l >> 4;
    int row0 = blockIdx.x * 16;

#pragma unroll
    for (int i = 0; i < 8; i++) {
        int idx = tid + i * 256;
        int row = idx >> 7, c4 = idx & 127;
        float4 v = *(const float4*)(x + (row0 + row) * 512 + c4 * 4);
        union { half2v h[2]; uint2 u; } cv;
        cv.h[0][0] = (_Float16)v.x; cv.h[0][1] = (_Float16)v.y;
        cv.h[1][0] = (_Float16)v.z; cv.h[1][1] = (_Float16)v.w;
        *(uint2*)(xs + row * XS_STRIDE + c4 * 4) = cv.u;
    }
    __syncthreads();

    const _Float16* arow = xs + m * XS_STRIDE + quad * 8;

    floatx4 acc[3];
#pragma unroll
    for (int i = 0; i < 3; i++) acc[i] = (floatx4)(0.f);

#pragma unroll 4
    for (int kc = 0; kc < 16; kc++) {
        half8v a = *(const half8v*)(arow + kc * 32);
#pragma unroll
        for (int ct = 0; ct < 3; ct++) {
            int ctg = wv * 3 + ct;
            half8v b = *(const half8v*)(Wt + (((ctg << 4) + kc) * 64 + l) * 8);
            acc[ct] = __builtin_amdgcn_mfma_f32_16x16x32_f16(a, b, acc[ct], 0, 0, 0);
        }
    }

#pragma unroll
    for (int ct = 0; ct < 3; ct++) {
        int ctg = wv * 3 + ct;
        int col = ctg * 16 + m;
        float bias = (ctg < 4) ? bq[col] : ((ctg < 8) ? bk[col - 64] : bv[col - 128]);
        if (ctg < 8) {
            _Float16* dst = (ctg < 4) ? Qh : Kh;
            float scl = (ctg < 4) ? LOG2E_OVER_8 : 1.0f;
            int dd = (ctg & 3) * 16 + m;
            int c = dd >> 5, quadQ = (dd >> 3) & 3, j = dd & 7;
#pragma unroll
            for (int r = 0; r < 4; r++) {
                int row = row0 + quad * 4 + r;
                int chunk = ((row >> 4) << 1) + c;
                dst[(chunk * 64 + quadQ * 16 + (row & 15)) * 8 + j] =
                    (_Float16)((acc[ct][r] + bias) * scl);
            }
        } else {
            int dt = ctg - 8;
            int t64 = row0 >> 6, ktp = (row0 >> 5) & 1, half = (row0 >> 4) & 1;
            int chunk = t64 * 8 + dt * 2 + ktp;
            union { _Float16 h[4]; unsigned long long u; } pk;
#pragma unroll
            for (int r = 0; r < 4; r++) pk.h[r] = (_Float16)(acc[ct][r] + bias);
            *(unsigned long long*)(Vh + (chunk * 64 + quad * 16 + m) * 8 + half * 4) = pk.u;
        }
    }
}

// ---------------- Kernel 2: attention, async LDS staging, variable split ----
// grid = 64qblk x ngrp (ngrp = spl*4; bid & (ngrp-1) -> XCD-pinned K/V slice).
// Block: 2 waves x 32 q; nt 64-key tiles (spl=8 -> 8 tiles, spl=4 -> 16).
// 16 KB K+V tiles via global_load_lds (zero VGPRs), double-buffered;
// [barrier][issue t+1][compute t] so the drain waits only for landed tile t.
__global__ __launch_bounds__(128) void attn_k(const _Float16* __restrict__ Qh,
                                              const _Float16* __restrict__ Kh,
                                              const _Float16* __restrict__ Vh,
                                              const int* __restrict__ mask,
                                              float* __restrict__ Np,
                                              float* __restrict__ Dp,
                                              int gshift, int nt) {
    __shared__ __align__(16) uint4 buf[2][1024];   // 2 x 16 KB

    int tid = threadIdx.x, l = tid & 63, wv = tid >> 6;   // wv 0/1
    int m = l & 15, quad = l >> 4;
    int bid = blockIdx.x;
    int grp = bid & ((1 << gshift) - 1), qblk = bid >> gshift;
    int os = grp >> 2, b = grp & 3;
    int q0 = qblk * 64 + wv * 32;
    int kpb = nt * 64;                    // keys per block

    const int* maskb = mask + b * 4096 + os * kpb;
    int az = 0;
    for (int i = 0; i < nt; i++) az |= (maskb[l + i * 64] == 0);
    const bool hasz = __any(az);

    // Q B-frags for this wave's 2 q-tiles
    int qt_g = (b * 4096 + q0) >> 4;
    half8v qf[2][2];
#pragma unroll
    for (int qt = 0; qt < 2; qt++)
#pragma unroll
        for (int c = 0; c < 2; c++)
            qf[qt][c] = *(const half8v*)(Qh + (((qt_g + qt) * 2 + c) * 64 + l) * 8);

    int tb0 = (b * 64 + os * nt) * 512;   // uint4 idx of tile 0
    const uint4* gsrc = ((wv == 0) ? (const uint4*)Kh : (const uint4*)Vh) + tb0;
    // wave 0 stages K (slots 0..7), wave 1 stages V (slots 8..15)

    floatx4 oacc[2][4];
#pragma unroll
    for (int qt = 0; qt < 2; qt++)
#pragma unroll
        for (int dt = 0; dt < 4; dt++) oacc[qt][dt] = (floatx4)(0.f);
    float dl[2] = {0.f, 0.f};

    typedef const __attribute__((address_space(1))) void gvoid;
    typedef __attribute__((address_space(3))) void lvoid;

    // issue tile 0
#pragma unroll
    for (int j = 0; j < 8; j++)
        __builtin_amdgcn_global_load_lds(
            (gvoid*)(gsrc + j * 64 + l),
            (lvoid*)(&buf[0][(wv * 8 + j) * 64]), 16, 0, 0);

#pragma unroll 2
    for (int t = 0; t < nt; t++) {
        __syncthreads();   // vmcnt(0) drain == wait for tile t (already landed)
        if (t + 1 < nt) {
            const uint4* gs = gsrc + (t + 1) * 512;
            uint4* bn = &buf[(t + 1) & 1][0];
#pragma unroll
            for (int j = 0; j < 8; j++)
                __builtin_amdgcn_global_load_lds(
                    (gvoid*)(gs + j * 64 + l),
                    (lvoid*)(bn + (wv * 8 + j) * 64), 16, 0, 0);
        }
        const unsigned char* bk = (const unsigned char*)&buf[t & 1][0];
        const unsigned char* bv = bk + 8192;
        uint4 vv[4];
#pragma unroll
        for (int sub = 0; sub < 4; sub++) {
            half8v k0 = *(const half8v*)(bk + (sub * 2 + 0) * 1024 + l * 16);
            half8v k1 = *(const half8v*)(bk + (sub * 2 + 1) * 1024 + l * 16);
            if ((sub & 1) == 0) {
#pragma unroll
                for (int dt = 0; dt < 4; dt++)
                    vv[dt] = *(const uint4*)(bv + (dt * 2 + (sub >> 1)) * 1024 + l * 16);
            }
            half4v pb[2];
#pragma unroll
            for (int qt = 0; qt < 2; qt++) {
                floatx4 sf = (floatx4)(0.f);
                sf = __builtin_amdgcn_mfma_f32_16x16x32_f16(k0, qf[qt][0], sf, 0, 0, 0);
                sf = __builtin_amdgcn_mfma_f32_16x16x32_f16(k1, qf[qt][1], sf, 0, 0, 0);
                float p0 = exp2f(sf[0]), p1 = exp2f(sf[1]);
                float p2 = exp2f(sf[2]), p3 = exp2f(sf[3]);
                dl[qt] += (p0 + p1) + (p2 + p3);
                if (hasz) {   // post-softmax -inf fill (rare path)
                    int kg = t * 64 + sub * 16 + quad * 4;
                    if (maskb[kg + 0] == 0) p0 = -__builtin_inff();
                    if (maskb[kg + 1] == 0) p1 = -__builtin_inff();
                    if (maskb[kg + 2] == 0) p2 = -__builtin_inff();
                    if (maskb[kg + 3] == 0) p3 = -__builtin_inff();
                }
                union { fp16x2 h[2]; half4v h4; } pu;
                pu.h[0] = __builtin_amdgcn_cvt_pkrtz(p0, p1);
                pu.h[1] = __builtin_amdgcn_cvt_pkrtz(p2, p3);
                pb[qt] = pu.h4;
            }
#pragma unroll
            for (int dt = 0; dt < 4; dt++) {
                union { uint4 u; half4v h[2]; } vc; vc.u = vv[dt];
                half4v va = vc.h[sub & 1];
                oacc[0][dt] = __builtin_amdgcn_mfma_f32_16x16x16f16(va, pb[0], oacc[0][dt], 0, 0, 0);
                oacc[1][dt] = __builtin_amdgcn_mfma_f32_16x16x16f16(va, pb[1], oacc[1][dt], 0, 0, 0);
            }
        }
    }

    // epilogue: den + O^T transpose via wave-private LDS (reuse buf)
    __syncthreads();
    float* Tw = (float*)(&buf[0][0]) + wv * (16 * 68);
    int rowb = os * 16384 + b * 4096 + q0;
#pragma unroll
    for (int qt = 0; qt < 2; qt++) {
        float dqt = dl[qt];
        dqt += __shfl_xor(dqt, 16, 64);
        dqt += __shfl_xor(dqt, 32, 64);
        if (l < 16) Dp[rowb + qt * 16 + l] = dqt;
#pragma unroll
        for (int dt = 0; dt < 4; dt++)
#pragma unroll
            for (int r = 0; r < 4; r++)
                Tw[m * 68 + dt * 16 + quad * 4 + r] = oacc[qt][dt][r];
        __builtin_amdgcn_s_waitcnt(0);
#pragma unroll
        for (int g = 0; g < 4; g++) {
            int idx = g * 64 + l;
            int row = idx >> 4, c4 = (idx & 15) * 4;
            float4 v = *(const float4*)(Tw + row * 68 + c4);
            *(float4*)(Np + (rowb + qt * 16 + row) * 64 + c4) = v;
        }
        __builtin_amdgcn_s_waitcnt(0);   // reads done before next qt overwrite
    }
}

// ---------------- Kernel 3: combine spl key-split partials ------------------
__global__ __launch_bounds__(256) void combine_k(const float* __restrict__ Np,
                                                 const float* __restrict__ Dp,
                                                 float* __restrict__ out,
                                                 int spl) {
    int g4 = blockIdx.x * 256 + threadIdx.x;   // 262144 float4 groups
    int row = g4 >> 4;
    float4 nu = make_float4(0.f, 0.f, 0.f, 0.f);
    float d = 0.f;
    for (int sp = 0; sp < spl; sp++) {
        float4 v = ((const float4*)Np)[sp * 262144 + g4];
        nu.x += v.x; nu.y += v.y; nu.z += v.z; nu.w += v.w;
        d += Dp[sp * 16384 + row];
    }
    float inv = 1.0f / d;
    ((float4*)out)[g4] = make_float4(nu.x * inv, nu.y * inv, nu.z * inv, nu.w * inv);
}

extern "C" void kernel_launch(void* const* d_in, const int* in_sizes, int n_in,
                              void* d_out, int out_size, void* d_ws, size_t ws_size,
                              hipStream_t stream) {
    const float* x  = (const float*)d_in[0];
    const int* mask = (const int*)d_in[1];
    const float* Wq = (const float*)d_in[2];
    const float* bq = (const float*)d_in[3];
    const float* Wk = (const float*)d_in[4];
    const float* bk = (const float*)d_in[5];
    const float* Wv = (const float*)d_in[6];
    const float* bv = (const float*)d_in[7];
    float* out = (float*)d_out;

    char* ws = (char*)d_ws;
    _Float16* Wt = (_Float16*)(ws);              // 192 KB frag-order
    _Float16* Qh = (_Float16*)(ws + 0x40000);    // 2 MB frag-order
    _Float16* Kh = (_Float16*)(ws + 0x240000);   // 2 MB frag-order
    _Float16* Vh = (_Float16*)(ws + 0x440000);   // 2 MB V^T frag-order
    float*    Dp = (float*)(ws + 0x640000);      // 512 KB [<=8][16384]
    float*    Np = (float*)(ws + 0x6C0000);      // spl * 4.19 MB

    // key-split 8 if workspace allows (Np = spl*4.19 MB), else verified spl=4
    size_t need8 = 0x6C0000 + (size_t)8 * 16384 * 64 * 4;
    int spl = (ws_size >= need8) ? 8 : 4;
    int gshift = (spl == 8) ? 5 : 4;      // ngrp = spl*4
    int nt = (spl == 8) ? 8 : 16;         // 64-key tiles per block

    wtrans_k<<<384, 256, 0, stream>>>(Wq, Wk, Wv, Wt);
    proj_k<<<1024, 256, 0, stream>>>(x, Wt, bq, bk, bv, Qh, Kh, Vh);
    attn_k<<<64 * 4 * spl, 128, 0, stream>>>(Qh, Kh, Vh, mask, Np, Dp, gshift, nt);
    combine_k<<<1024, 256, 0, stream>>>(Np, Dp, out, spl);
}

// Round 12
// 144.124 us; speedup vs baseline: 1.0697x; 1.0697x over previous
//
#include <hip/hip_runtime.h>
#include <hip/hip_bf16.h>

typedef _Float16 half8v __attribute__((ext_vector_type(8)));
typedef _Float16 half4v __attribute__((ext_vector_type(4)));
typedef _Float16 half2v __attribute__((ext_vector_type(2)));
typedef __fp16   fp16x2 __attribute__((ext_vector_type(2)));
typedef __attribute__((ext_vector_type(4))) float floatx4;

#define LOG2E_OVER_8 0.18033688011112042f

// ===== Frag-order layouts (verified r9-r11) =================================
// Kh chunk(t16,c): ((t16*2+c)*64 + quad*16 + m)*8 halves  (A-frag 16x16x32)
// Qh: same with m=q%16. Vh chunk(t64,dt,ktp): (((t64*8)+dt*2+ktp)*64+quad*16+m)*8
// Wt: ((ctg*16+kc)*64 + quad*16 + m)*8
// => every frag load = 64 lanes x contiguous 16B = 1 KB coalesced global read.

// ---------------- Kernel 0: W -> frag-order Wt fp16 -------------------------
__global__ __launch_bounds__(256) void wtrans_k(const float* __restrict__ Wq,
                                                const float* __restrict__ Wk,
                                                const float* __restrict__ Wv,
                                                _Float16* __restrict__ Wt) {
    int idx = blockIdx.x * 256 + threadIdx.x;   // 98304 = 3*512*64
    int p = idx >> 15, rem = idx & 32767;
    int k = rem >> 6;      // input row
    int n = rem & 63;      // input col (lane-fast -> coalesced read)
    const float* W = (p == 0) ? Wq : ((p == 1) ? Wk : Wv);
    int ctg = p * 4 + (n >> 4), m = n & 15;
    int kc = k >> 5, quad = (k >> 3) & 3, j = k & 7;
    Wt[(((ctg << 4) + kc) * 64 + (quad << 4) + m) * 8 + j] = (_Float16)W[k * 64 + n];
}

// ---------------- Kernel 1: QKV projection (verified r9-r11) ----------------
#define XS_STRIDE 536
__global__ __launch_bounds__(256) void proj_k(const float* __restrict__ x,
                                              const _Float16* __restrict__ Wt,
                                              const float* __restrict__ bq,
                                              const float* __restrict__ bk,
                                              const float* __restrict__ bv,
                                              _Float16* __restrict__ Qh,
                                              _Float16* __restrict__ Kh,
                                              _Float16* __restrict__ Vh) {
    __shared__ _Float16 xs[16 * XS_STRIDE];

    int tid = threadIdx.x, l = tid & 63, wv = tid >> 6;
    int m = l & 15, quad = l >> 4;
    int row0 = blockIdx.x * 16;

#pragma unroll
    for (int i = 0; i < 8; i++) {
        int idx = tid + i * 256;
        int row = idx >> 7, c4 = idx & 127;
        float4 v = *(const float4*)(x + (row0 + row) * 512 + c4 * 4);
        union { half2v h[2]; uint2 u; } cv;
        cv.h[0][0] = (_Float16)v.x; cv.h[0][1] = (_Float16)v.y;
        cv.h[1][0] = (_Float16)v.z; cv.h[1][1] = (_Float16)v.w;
        *(uint2*)(xs + row * XS_STRIDE + c4 * 4) = cv.u;
    }
    __syncthreads();

    const _Float16* arow = xs + m * XS_STRIDE + quad * 8;

    floatx4 acc[3];
#pragma unroll
    for (int i = 0; i < 3; i++) acc[i] = (floatx4)(0.f);

#pragma unroll 4
    for (int kc = 0; kc < 16; kc++) {
        half8v a = *(const half8v*)(arow + kc * 32);
#pragma unroll
        for (int ct = 0; ct < 3; ct++) {
            int ctg = wv * 3 + ct;
            half8v b = *(const half8v*)(Wt + (((ctg << 4) + kc) * 64 + l) * 8);
            acc[ct] = __builtin_amdgcn_mfma_f32_16x16x32_f16(a, b, acc[ct], 0, 0, 0);
        }
    }

#pragma unroll
    for (int ct = 0; ct < 3; ct++) {
        int ctg = wv * 3 + ct;
        int col = ctg * 16 + m;
        float bias = (ctg < 4) ? bq[col] : ((ctg < 8) ? bk[col - 64] : bv[col - 128]);
        if (ctg < 8) {
            _Float16* dst = (ctg < 4) ? Qh : Kh;
            float scl = (ctg < 4) ? LOG2E_OVER_8 : 1.0f;
            int dd = (ctg & 3) * 16 + m;
            int c = dd >> 5, quadQ = (dd >> 3) & 3, j = dd & 7;
#pragma unroll
            for (int r = 0; r < 4; r++) {
                int row = row0 + quad * 4 + r;
                int chunk = ((row >> 4) << 1) + c;
                dst[(chunk * 64 + quadQ * 16 + (row & 15)) * 8 + j] =
                    (_Float16)((acc[ct][r] + bias) * scl);
            }
        } else {
            int dt = ctg - 8;
            int t64 = row0 >> 6, ktp = (row0 >> 5) & 1, half = (row0 >> 4) & 1;
            int chunk = t64 * 8 + dt * 2 + ktp;
            union { _Float16 h[4]; unsigned long long u; } pk;
#pragma unroll
            for (int r = 0; r < 4; r++) pk.h[r] = (_Float16)(acc[ct][r] + bias);
            *(unsigned long long*)(Vh + (chunk * 64 + quad * 16 + m) * 8 + half * 4) = pk.u;
        }
    }
}

// ---------------- Kernel 2: attention, barrier-free direct-L2 frags ---------
// grid = qblk x ngrp (ngrp = spl*4; bid & (ngrp-1) -> XCD-pinned K/V slice).
// Block: 4 fully independent waves (no __syncthreads), same keys, different
// 32-q strips (L1 reuse of the shared K/V stream). All frag loads are 1 KB
// coalesced global_load_dwordx4 from frag-order Kh/Vh (L2-resident).
template <int NT>
__global__ __launch_bounds__(256) void attn_k(const _Float16* __restrict__ Qh,
                                              const _Float16* __restrict__ Kh,
                                              const _Float16* __restrict__ Vh,
                                              const int* __restrict__ mask,
                                              float* __restrict__ Np,
                                              float* __restrict__ Dp,
                                              int gshift) {
    __shared__ float T[4][16 * 68];   // wave-private epilogue transpose (17.4 KB)

    int tid = threadIdx.x, l = tid & 63, wv = tid >> 6;
    int m = l & 15, quad = l >> 4;
    int bid = blockIdx.x;
    int grp = bid & ((1 << gshift) - 1), qblk = bid >> gshift;
    int os = grp >> 2, b = grp & 3;
    int q0 = qblk * 128 + wv * 32;

    const int* maskb = mask + b * 4096 + os * (NT * 64);
    int az = 0;
#pragma unroll
    for (int i = 0; i < NT; i++) az |= (maskb[l + i * 64] == 0);
    const bool hasz = __any(az);

    // Q B-frags for this wave's 2 q-tiles
    int qt_g = (b * 4096 + q0) >> 4;
    half8v qf[2][2];
#pragma unroll
    for (int qt = 0; qt < 2; qt++)
#pragma unroll
        for (int c = 0; c < 2; c++)
            qf[qt][c] = *(const half8v*)(Qh + (((qt_g + qt) * 2 + c) * 64 + l) * 8);

    int tb0 = (b * 64 + os * NT) * 512;   // uint4 idx of this slice's tile 0
    const uint4* kh4 = (const uint4*)Kh + tb0;
    const uint4* vh4 = (const uint4*)Vh + tb0;

    floatx4 oacc[2][4];
#pragma unroll
    for (int qt = 0; qt < 2; qt++)
#pragma unroll
        for (int dt = 0; dt < 4; dt++) oacc[qt][dt] = (floatx4)(0.f);
    float dl[2] = {0.f, 0.f};

#pragma unroll 2
    for (int t = 0; t < NT; t++) {
        const uint4* kt4 = kh4 + t * 512;
        const uint4* vt4 = vh4 + t * 512;
        uint4 vv[4];
#pragma unroll
        for (int sub = 0; sub < 4; sub++) {
            union { uint4 u; half8v h; } ku0, ku1;
            ku0.u = kt4[(sub * 2 + 0) * 64 + l];
            ku1.u = kt4[(sub * 2 + 1) * 64 + l];
            if ((sub & 1) == 0) {
#pragma unroll
                for (int dt = 0; dt < 4; dt++)
                    vv[dt] = vt4[(dt * 2 + (sub >> 1)) * 64 + l];
            }
            half4v pb[2];
#pragma unroll
            for (int qt = 0; qt < 2; qt++) {
                floatx4 sf = (floatx4)(0.f);
                sf = __builtin_amdgcn_mfma_f32_16x16x32_f16(ku0.h, qf[qt][0], sf, 0, 0, 0);
                sf = __builtin_amdgcn_mfma_f32_16x16x32_f16(ku1.h, qf[qt][1], sf, 0, 0, 0);
                float p0 = exp2f(sf[0]), p1 = exp2f(sf[1]);
                float p2 = exp2f(sf[2]), p3 = exp2f(sf[3]);
                dl[qt] += (p0 + p1) + (p2 + p3);
                if (hasz) {   // post-softmax -inf fill (rare path)
                    int kg = t * 64 + sub * 16 + quad * 4;
                    if (maskb[kg + 0] == 0) p0 = -__builtin_inff();
                    if (maskb[kg + 1] == 0) p1 = -__builtin_inff();
                    if (maskb[kg + 2] == 0) p2 = -__builtin_inff();
                    if (maskb[kg + 3] == 0) p3 = -__builtin_inff();
                }
                union { fp16x2 h[2]; half4v h4; } pu;
                pu.h[0] = __builtin_amdgcn_cvt_pkrtz(p0, p1);
                pu.h[1] = __builtin_amdgcn_cvt_pkrtz(p2, p3);
                pb[qt] = pu.h4;
            }
#pragma unroll
            for (int dt = 0; dt < 4; dt++) {
                union { uint4 u; half4v h[2]; } vc; vc.u = vv[dt];
                half4v va = vc.h[sub & 1];
                oacc[0][dt] = __builtin_amdgcn_mfma_f32_16x16x16f16(va, pb[0], oacc[0][dt], 0, 0, 0);
                oacc[1][dt] = __builtin_amdgcn_mfma_f32_16x16x16f16(va, pb[1], oacc[1][dt], 0, 0, 0);
            }
        }
    }

    // epilogue: den + O^T transpose via wave-private LDS (no barrier)
    float* Tw = &T[wv][0];
    int rowb = os * 16384 + b * 4096 + q0;
#pragma unroll
    for (int qt = 0; qt < 2; qt++) {
        float dqt = dl[qt];
        dqt += __shfl_xor(dqt, 16, 64);
        dqt += __shfl_xor(dqt, 32, 64);
        if (l < 16) Dp[rowb + qt * 16 + l] = dqt;
#pragma unroll
        for (int dt = 0; dt < 4; dt++)
#pragma unroll
            for (int r = 0; r < 4; r++)
                Tw[m * 68 + dt * 16 + quad * 4 + r] = oacc[qt][dt][r];
        __builtin_amdgcn_s_waitcnt(0);   // wave-private LDS: lgkm drain only
#pragma unroll
        for (int g = 0; g < 4; g++) {
            int idx = g * 64 + l;
            int row = idx >> 4, c4 = (idx & 15) * 4;
            float4 v = *(const float4*)(Tw + row * 68 + c4);
            *(float4*)(Np + (rowb + qt * 16 + row) * 64 + c4) = v;
        }
        __builtin_amdgcn_s_waitcnt(0);   // reads done before next qt overwrite
    }
}

// ---------------- Kernel 3: combine spl key-split partials ------------------
__global__ __launch_bounds__(256) void combine_k(const float* __restrict__ Np,
                                                 const float* __restrict__ Dp,
                                                 float* __restrict__ out,
                                                 int spl) {
    int g4 = blockIdx.x * 256 + threadIdx.x;   // 262144 float4 groups
    int row = g4 >> 4;
    float4 nu = make_float4(0.f, 0.f, 0.f, 0.f);
    float d = 0.f;
    for (int sp = 0; sp < spl; sp++) {
        float4 v = ((const float4*)Np)[sp * 262144 + g4];
        nu.x += v.x; nu.y += v.y; nu.z += v.z; nu.w += v.w;
        d += Dp[sp * 16384 + row];
    }
    float inv = 1.0f / d;
    ((float4*)out)[g4] = make_float4(nu.x * inv, nu.y * inv, nu.z * inv, nu.w * inv);
}

extern "C" void kernel_launch(void* const* d_in, const int* in_sizes, int n_in,
                              void* d_out, int out_size, void* d_ws, size_t ws_size,
                              hipStream_t stream) {
    const float* x  = (const float*)d_in[0];
    const int* mask = (const int*)d_in[1];
    const float* Wq = (const float*)d_in[2];
    const float* bq = (const float*)d_in[3];
    const float* Wk = (const float*)d_in[4];
    const float* bk = (const float*)d_in[5];
    const float* Wv = (const float*)d_in[6];
    const float* bv = (const float*)d_in[7];
    float* out = (float*)d_out;

    char* ws = (char*)d_ws;
    _Float16* Wt = (_Float16*)(ws);              // 192 KB frag-order
    _Float16* Qh = (_Float16*)(ws + 0x40000);    // 2 MB frag-order
    _Float16* Kh = (_Float16*)(ws + 0x240000);   // 2 MB frag-order
    _Float16* Vh = (_Float16*)(ws + 0x440000);   // 2 MB V^T frag-order
    float*    Dp = (float*)(ws + 0x640000);      // 512 KB [<=8][16384]
    float*    Np = (float*)(ws + 0x6C0000);      // spl * 4.19 MB

    // key-split 8 if workspace allows (Np = spl*4.19 MB), else spl=4
    size_t need8 = 0x6C0000 + (size_t)8 * 16384 * 64 * 4;
    int spl = (ws_size >= need8) ? 8 : 4;

    wtrans_k<<<384, 256, 0, stream>>>(Wq, Wk, Wv, Wt);
    proj_k<<<1024, 256, 0, stream>>>(x, Wt, bq, bk, bv, Qh, Kh, Vh);
    if (spl == 8)
        attn_k<8><<<32 * 32, 256, 0, stream>>>(Qh, Kh, Vh, mask, Np, Dp, 5);
    else
        attn_k<16><<<32 * 16, 256, 0, stream>>>(Qh, Kh, Vh, mask, Np, Dp, 4);
    combine_k<<<1024, 256, 0, stream>>>(Np, Dp, out, spl);
}